// Round 1
// 518.755 us; speedup vs baseline: 1.0040x; 1.0040x over previous
//
#include <hip/hip_runtime.h>

// out[b,i,j,d] = pe[clamp(128 + j - i, 0, 256)][d]
// B=4, S=512, D=128 -> out = 512 MiB fp32. Pure write-BW-bound; floor ~86 us
// at the 6.25 TB/s the harness's own fillBufferAligned achieves on this chip.
//
// R3 change: break the load->store dependency chain.
// With grid = 8192 x 256 = 2^21 threads and TOTAL4 = 16 * 2^21 exactly, each
// thread's 16 grid-stride iterations have FIXED d4 and j; i cycles through
// only 4 values (i0 + 128*(k&3)) and b = k>>2. So each thread needs only
// 4 distinct pe values. Preload those 4 f32x4 into registers (coalesced,
// L2-resident reads), then issue 16 independent global_store_dwordx4 with
// no vmcnt wait in between -- same structure as the 6.25 TB/s fill kernel.
//
// (R2 lesson kept: no nontemporal stores -- nt/sc flags were ~5x slower.)

typedef float f32x4 __attribute__((ext_vector_type(4)));

constexpr int MAXPOS = 128;

__global__ __launch_bounds__(256) void rel_pe_kernel(
    const f32x4* __restrict__ pe4,   // [512][32] f32x4 (only rows 0..256 used)
    f32x4* __restrict__ out4)
{
    const int idx = blockIdx.x * blockDim.x + threadIdx.x;  // 0 .. 2^21-1
    const int d4 = idx & 31;          // f32x4 index within D=128 row
    const int j  = (idx >> 5) & 511;
    const int i0 = idx >> 14;         // 0..127 (i-block base)

    // Preload the 4 distinct pe values this thread will ever store.
    f32x4 v[4];
#pragma unroll
    for (int m = 0; m < 4; ++m) {
        int rel = MAXPOS + j - (i0 + (m << 7));             // i = i0 + 128*m
        rel = rel < 0 ? 0 : (rel > 2 * MAXPOS ? 2 * MAXPOS : rel);
        v[m] = pe4[rel * 32 + d4];
    }

    // 16 independent, fully-coalesced dwordx4 stores (4 i-blocks x 4 b-copies).
#pragma unroll
    for (int k = 0; k < 16; ++k) {
        out4[idx + (k << 21)] = v[k & 3];
    }
}

extern "C" void kernel_launch(void* const* d_in, const int* in_sizes, int n_in,
                              void* d_out, int out_size, void* d_ws, size_t ws_size,
                              hipStream_t stream) {
    // d_in[0] = x (int32, unused -- shape only), d_in[1] = pe (float32 [512][128])
    const f32x4* pe4 = (const f32x4*)d_in[1];
    f32x4* out4 = (f32x4*)d_out;

    const int threads = 256;
    const int blocks  = 8192;   // 2^21 threads x 16 f32x4 stores = full output
    rel_pe_kernel<<<blocks, threads, 0, stream>>>(pe4, out4);
}